// Round 7
// baseline (164.879 us; speedup 1.0000x reference)
//
#include <hip/hip_runtime.h>
#include <hip/hip_bf16.h>
#include <cstdint>
#include <cstddef>
#include <math.h>

#define D 256
#define TEMP_INV 2.0f       // 1 / TEMPERATURE, TEMPERATURE = 0.5
#define EPS_NORM 1e-8f
#define NTILES 2080         // 64*65/2 upper-triangular 128x128 tiles

typedef __attribute__((ext_vector_type(8))) short bf16x8;
typedef __attribute__((ext_vector_type(4))) float f32x4;

// ---------------- kernel 1: normalize rows, write bf16 zn ----------------
__global__ void __launch_bounds__(256) normalize_rows(
    const float* __restrict__ zi, const float* __restrict__ zj,
    __hip_bfloat16* __restrict__ zn, float* __restrict__ denom, int B) {
  int row = blockIdx.x * 4 + (threadIdx.x >> 6);
  int lane = threadIdx.x & 63;
  if (threadIdx.x < 4) denom[blockIdx.x * 4 + threadIdx.x] = 0.0f;
  const float* src = (row < B) ? (zi + (size_t)row * D)
                               : (zj + (size_t)(row - B) * D);
  float4 v = ((const float4*)src)[lane];
  float ss = v.x * v.x + v.y * v.y + v.z * v.z + v.w * v.w;
  for (int off = 32; off; off >>= 1) ss += __shfl_xor(ss, off);
  float rn = 1.0f / fmaxf(sqrtf(ss), EPS_NORM);
  union { ushort4 u; __hip_bfloat16 h[4]; } o;
  o.h[0] = __float2bfloat16(v.x * rn);
  o.h[1] = __float2bfloat16(v.y * rn);
  o.h[2] = __float2bfloat16(v.z * rn);
  o.h[3] = __float2bfloat16(v.w * rn);
  ((ushort4*)zn)[(size_t)row * (D / 4) + lane] = o.u;
}

// ---------------- kernel 2: fused sim GEMM + exp + masked row/col sums ---
// Upper-triangular 128x128 tiles, one-shot 2080 blocks, BK=64.
// Staging: lane-sequential float4 global loads (coalesced -> few L2
// requests) then ds_write_b128 with XOR swizzle on the LDS ADDRESS.
// LDS(r,c') = global chunk c'^(r&7) => ds_read_b128 fragments conflict-free
// (verified 0 conflicts, round 4). Next slab's loads issue before compute.
// __launch_bounds__(256,2): 2 waves/SIMD -> 256-reg cap; the ~190-reg
// working set (64 acc + 32 staging + 32 frags + addr) fits WITHOUT spill.
// (256,3) and default both spilled to scratch: rounds 6 / 2.
__device__ __forceinline__ void decode_tile(int t, int Nb, int& by, int& bx) {
  float fb = (2.0f * Nb + 1.0f -
              sqrtf((float)((2 * Nb + 1) * (2 * Nb + 1) - 8 * t))) * 0.5f;
  int y = (int)fb;
  while ((y + 1) * Nb - ((y + 1) * y) / 2 <= t) ++y;
  while (y * Nb - (y * (y - 1)) / 2 > t) --y;
  by = y;
  bx = y + (t - (y * Nb - (y * (y - 1)) / 2));
}

__global__ void __launch_bounds__(256, 2) ntxent_gemm(
    const __hip_bfloat16* __restrict__ zn,
    float* __restrict__ denom, float* __restrict__ pos, int B) {
  __shared__ __align__(16) __hip_bfloat16 Ash[128 * 64];  // 16 KB
  __shared__ __align__(16) __hip_bfloat16 Bsh[128 * 64];  // 16 KB

  const int Nb = (2 * B) / 128;  // 64
  int by, bx;
  decode_tile(blockIdx.x, Nb, by, bx);
  const int bm = by * 128;
  const int bn = bx * 128;
  const bool isDiag = (by == bx);
  const bool isPos = (bx == by + B / 128);

  const int tid = threadIdx.x;
  const int wid = tid >> 6;
  const int lane = tid & 63;
  const int wy = wid >> 1, wx = wid & 1;
  const int wrow0 = wid * 32;

  const int r8 = lane >> 3;     // row within 8-row staging group
  const int c8 = lane & 7;      // 16B chunk (global order: coalesced)

  const int frow = lane & 15;
  const int quad = lane >> 4;
  const int f7 = frow & 7;

  f32x4 acc[4][4] = {};
  float4 va[4], vb[4];

  // per-lane global base pointers for staging (row fixed, k advances)
  const __hip_bfloat16* pa[4];
  const __hip_bfloat16* pb[4];
#pragma unroll
  for (int s = 0; s < 4; ++s) {
    int r = wrow0 + s * 8 + r8;
    pa[s] = zn + (size_t)(bm + r) * D + c8 * 8;
    pb[s] = zn + (size_t)(bn + r) * D + c8 * 8;
  }

  // prologue: load slab 0 (lane-sequential within each 128B row segment)
#pragma unroll
  for (int s = 0; s < 4; ++s) {
    va[s] = *(const float4*)pa[s];
    vb[s] = *(const float4*)pb[s];
  }

#pragma unroll
  for (int k0i = 0; k0i < 4; ++k0i) {
    __syncthreads();  // WAR: previous slab's LDS reads complete
#pragma unroll
    for (int s = 0; s < 4; ++s) {
      int r = wrow0 + s * 8 + r8;
      int swz = c8 ^ (r & 7);
      *(float4*)&Ash[r * 64 + swz * 8] = va[s];
      *(float4*)&Bsh[r * 64 + swz * 8] = vb[s];
    }
    __syncthreads();
    if (k0i < 3) {  // issue next slab's loads; latency hides under compute
      const int k0n = (k0i + 1) * 64;
#pragma unroll
      for (int s = 0; s < 4; ++s) {
        va[s] = *(const float4*)(pa[s] + k0n);
        vb[s] = *(const float4*)(pb[s] + k0n);
      }
    }
#pragma unroll
    for (int kk = 0; kk < 2; ++kk) {
      bf16x8 a[4], b[4];
#pragma unroll
      for (int i = 0; i < 4; ++i)
        a[i] = *(const bf16x8*)
            &Ash[(wy * 64 + i * 16 + frow) * 64 + ((kk * 4 + quad) ^ f7) * 8];
#pragma unroll
      for (int j = 0; j < 4; ++j)
        b[j] = *(const bf16x8*)
            &Bsh[(wx * 64 + j * 16 + frow) * 64 + ((kk * 4 + quad) ^ f7) * 8];
#pragma unroll
      for (int i = 0; i < 4; ++i)
#pragma unroll
        for (int j = 0; j < 4; ++j)
          acc[i][j] =
              __builtin_amdgcn_mfma_f32_16x16x32_bf16(a[i], b[j], acc[i][j], 0, 0, 0);
    }
  }

  // epilogue: C/D layout col = lane&15, row = quad*4 + reg
  const int colq = lane & 15;
  float cs[4] = {0.0f, 0.0f, 0.0f, 0.0f};
#pragma unroll
  for (int i = 0; i < 4; ++i) {
#pragma unroll
    for (int r = 0; r < 4; ++r) {
      int row = bm + wy * 64 + i * 16 + quad * 4 + r;
      float rs = 0.0f;
#pragma unroll
      for (int j = 0; j < 4; ++j) {
        int col = bn + wx * 64 + j * 16 + colq;
        float v = acc[i][j][r];
        float e = __expf(v * TEMP_INV);
        e = (isDiag && col == row) ? 0.0f : e;
        rs += e;
        cs[j] += e;
        if (isPos && col == row + B) { pos[row] = v; pos[col] = v; }
      }
      rs += __shfl_xor(rs, 1);
      rs += __shfl_xor(rs, 2);
      rs += __shfl_xor(rs, 4);
      rs += __shfl_xor(rs, 8);
      if (colq == 0) atomicAdd(&denom[row], rs);
    }
  }
  if (!isDiag) {
#pragma unroll
    for (int j = 0; j < 4; ++j) {
      float c = cs[j];
      c += __shfl_xor(c, 16);
      c += __shfl_xor(c, 32);
      if (quad == 0) atomicAdd(&denom[bn + wx * 64 + j * 16 + colq], c);
    }
  }
}

// ---------------- kernel 3: finalize loss scalar -------------------------
__global__ void __launch_bounds__(1024) finalize(
    const float* __restrict__ denom, const float* __restrict__ pos,
    float* __restrict__ out, int N) {
  __shared__ float red[16];
  const int tid = threadIdx.x;
  float s = 0.0f;
  for (int i = tid; i < N / 4; i += 1024) {
    float4 d = ((const float4*)denom)[i];
    float4 p = ((const float4*)pos)[i];
    s += __logf(d.x) - p.x * TEMP_INV;
    s += __logf(d.y) - p.y * TEMP_INV;
    s += __logf(d.z) - p.z * TEMP_INV;
    s += __logf(d.w) - p.w * TEMP_INV;
  }
  for (int off = 32; off; off >>= 1) s += __shfl_xor(s, off);
  if ((tid & 63) == 0) red[tid >> 6] = s;
  __syncthreads();
  if (tid < 16) {
    s = red[tid];
    s += __shfl_xor(s, 1);
    s += __shfl_xor(s, 2);
    s += __shfl_xor(s, 4);
    s += __shfl_xor(s, 8);
    if (tid == 0) out[0] = s / (float)N;
  }
}

extern "C" void kernel_launch(void* const* d_in, const int* in_sizes, int n_in,
                              void* d_out, int out_size, void* d_ws, size_t ws_size,
                              hipStream_t stream) {
  const float* zi = (const float*)d_in[0];
  const float* zj = (const float*)d_in[1];
  const int B = in_sizes[0] / D;  // 4096
  const int N = 2 * B;            // 8192

  __hip_bfloat16* zn = (__hip_bfloat16*)d_ws;
  float* denom = (float*)((char*)d_ws + (size_t)N * D * sizeof(__hip_bfloat16));
  float* pos = denom + N;

  normalize_rows<<<N / 4, 256, 0, stream>>>(zi, zj, zn, denom, B);
  ntxent_gemm<<<NTILES, 256, 0, stream>>>(zn, denom, pos, B);
  finalize<<<1, 1024, 0, stream>>>(denom, pos, (float*)d_out, N);
}

// Round 8
// 107.887 us; speedup vs baseline: 1.5283x; 1.5283x over previous
//
#include <hip/hip_runtime.h>
#include <hip/hip_bf16.h>
#include <cstdint>
#include <cstddef>
#include <math.h>

#define D 256
#define TEMP_INV 2.0f       // 1 / TEMPERATURE, TEMPERATURE = 0.5
#define EPS_NORM 1e-8f
#define NTILES 2080         // 64*65/2 upper-triangular 128x128 tiles

typedef __attribute__((ext_vector_type(8))) short bf16x8;
typedef __attribute__((ext_vector_type(4))) float f32x4;

// ---------------- kernel 1: normalize rows, write bf16 zn ----------------
// 512 blocks x 4 waves, grid-stride over 8192 rows (4 rows/wave).
__global__ void __launch_bounds__(256) normalize_rows(
    const float* __restrict__ zi, const float* __restrict__ zj,
    __hip_bfloat16* __restrict__ zn, float* __restrict__ denom, int B) {
  const int wid = threadIdx.x >> 6;
  const int lane = threadIdx.x & 63;
  if (threadIdx.x < 16) denom[blockIdx.x * 16 + threadIdx.x] = 0.0f;
#pragma unroll
  for (int it = 0; it < 4; ++it) {
    int row = it * 2048 + blockIdx.x * 4 + wid;
    const float* src = (row < B) ? (zi + (size_t)row * D)
                                 : (zj + (size_t)(row - B) * D);
    float4 v = ((const float4*)src)[lane];
    float ss = v.x * v.x + v.y * v.y + v.z * v.z + v.w * v.w;
    for (int off = 32; off; off >>= 1) ss += __shfl_xor(ss, off);
    float rn = 1.0f / fmaxf(sqrtf(ss), EPS_NORM);
    union { ushort4 u; __hip_bfloat16 h[4]; } o;
    o.h[0] = __float2bfloat16(v.x * rn);
    o.h[1] = __float2bfloat16(v.y * rn);
    o.h[2] = __float2bfloat16(v.z * rn);
    o.h[3] = __float2bfloat16(v.w * rn);
    ((ushort4*)zn)[(size_t)row * (D / 4) + lane] = o.u;
  }
}

// ---------------- kernel 2: fused sim GEMM + exp + masked row/col sums ---
// Upper-triangular 128x128 tiles, one-shot 2080 blocks, BK=64.
// Staging: lane-SEQUENTIAL float4 global loads (TA-mergeable -> 64B+
// requests; breaks the ~112 req/cyc wall of swizzled-source
// global_load_lds seen in R4/R5), then ds_write_b128 with the XOR swizzle
// on the LDS ADDRESS (write pattern: 0 conflicts measured R6/R7; read
// pattern: 0 conflicts measured R4). NO prefetch, NO float4 arrays live
// across barriers (that aggregate-liveness shape scratch-spilled in
// R2/R6/R7): staging uses named scalars consumed in-iteration.
__device__ __forceinline__ void decode_tile(int t, int Nb, int& by, int& bx) {
  float fb = (2.0f * Nb + 1.0f -
              sqrtf((float)((2 * Nb + 1) * (2 * Nb + 1) - 8 * t))) * 0.5f;
  int y = (int)fb;
  while ((y + 1) * Nb - ((y + 1) * y) / 2 <= t) ++y;
  while (y * Nb - (y * (y - 1)) / 2 > t) --y;
  by = y;
  bx = y + (t - (y * Nb - (y * (y - 1)) / 2));
}

__global__ void ntxent_gemm(
    const __hip_bfloat16* __restrict__ zn,
    float* __restrict__ denom, float* __restrict__ pos, int B) {
  __shared__ __align__(16) __hip_bfloat16 Ash[128 * 64];  // 16 KB
  __shared__ __align__(16) __hip_bfloat16 Bsh[128 * 64];  // 16 KB

  const int Nb = (2 * B) / 128;  // 64
  int by, bx;
  decode_tile(blockIdx.x, Nb, by, bx);
  const int bm = by * 128;
  const int bn = bx * 128;
  const bool isDiag = (by == bx);
  const bool isPos = (bx == by + B / 128);

  const int tid = threadIdx.x;
  const int wid = tid >> 6;
  const int lane = tid & 63;
  const int wy = wid >> 1, wx = wid & 1;
  const int wrow0 = wid * 32;

  const int lr = lane >> 3;     // row within 8-row staging group (== r&7)
  const int c8 = lane & 7;      // 16B chunk, SEQUENTIAL in global memory

  const int frow = lane & 15;
  const int quad = lane >> 4;
  const int f7 = frow & 7;

  f32x4 acc[4][4] = {};

  // staging addresses: row r(s) = wrow0 + s*8 + lr; global byte col = c8*16
  const __hip_bfloat16* gA = zn + (size_t)(bm + wrow0 + lr) * D + c8 * 8;
  const __hip_bfloat16* gB = zn + (size_t)(bn + wrow0 + lr) * D + c8 * 8;
  // LDS write: row r, chunk c8 ^ (r&7); r&7 == lr for every s (s*8 step)
  const int ldsoff = (wrow0 + lr) * 64 + (c8 ^ lr) * 8;

#pragma unroll
  for (int k0i = 0; k0i < 4; ++k0i) {
    const int k0 = k0i * 64;
    // lane-sequential coalesced loads (named scalars, in-iteration lifetime)
    float4 va0 = *(const float4*)(gA + 0 * 8 * D + k0);
    float4 va1 = *(const float4*)(gA + 1 * 8 * D + k0);
    float4 va2 = *(const float4*)(gA + 2 * 8 * D + k0);
    float4 va3 = *(const float4*)(gA + 3 * 8 * D + k0);
    float4 vb0 = *(const float4*)(gB + 0 * 8 * D + k0);
    float4 vb1 = *(const float4*)(gB + 1 * 8 * D + k0);
    float4 vb2 = *(const float4*)(gB + 2 * 8 * D + k0);
    float4 vb3 = *(const float4*)(gB + 3 * 8 * D + k0);
    __syncthreads();  // WAR: previous slab's LDS reads complete
    *(float4*)&Ash[ldsoff + 0 * 8 * 64] = va0;
    *(float4*)&Ash[ldsoff + 1 * 8 * 64] = va1;
    *(float4*)&Ash[ldsoff + 2 * 8 * 64] = va2;
    *(float4*)&Ash[ldsoff + 3 * 8 * 64] = va3;
    *(float4*)&Bsh[ldsoff + 0 * 8 * 64] = vb0;
    *(float4*)&Bsh[ldsoff + 1 * 8 * 64] = vb1;
    *(float4*)&Bsh[ldsoff + 2 * 8 * 64] = vb2;
    *(float4*)&Bsh[ldsoff + 3 * 8 * 64] = vb3;
    __syncthreads();
#pragma unroll
    for (int kk = 0; kk < 2; ++kk) {
      bf16x8 a[4], b[4];
#pragma unroll
      for (int i = 0; i < 4; ++i)
        a[i] = *(const bf16x8*)
            &Ash[(wy * 64 + i * 16 + frow) * 64 + ((kk * 4 + quad) ^ f7) * 8];
#pragma unroll
      for (int j = 0; j < 4; ++j)
        b[j] = *(const bf16x8*)
            &Bsh[(wx * 64 + j * 16 + frow) * 64 + ((kk * 4 + quad) ^ f7) * 8];
#pragma unroll
      for (int i = 0; i < 4; ++i)
#pragma unroll
        for (int j = 0; j < 4; ++j)
          acc[i][j] =
              __builtin_amdgcn_mfma_f32_16x16x32_bf16(a[i], b[j], acc[i][j], 0, 0, 0);
    }
  }

  // epilogue: C/D layout col = lane&15, row = quad*4 + reg
  const int colq = lane & 15;
  float cs[4] = {0.0f, 0.0f, 0.0f, 0.0f};
#pragma unroll
  for (int i = 0; i < 4; ++i) {
#pragma unroll
    for (int r = 0; r < 4; ++r) {
      int row = bm + wy * 64 + i * 16 + quad * 4 + r;
      float rs = 0.0f;
#pragma unroll
      for (int j = 0; j < 4; ++j) {
        int col = bn + wx * 64 + j * 16 + colq;
        float v = acc[i][j][r];
        float e = __expf(v * TEMP_INV);
        e = (isDiag && col == row) ? 0.0f : e;
        rs += e;
        cs[j] += e;
        if (isPos && col == row + B) { pos[row] = v; pos[col] = v; }
      }
      rs += __shfl_xor(rs, 1);
      rs += __shfl_xor(rs, 2);
      rs += __shfl_xor(rs, 4);
      rs += __shfl_xor(rs, 8);
      if (colq == 0) atomicAdd(&denom[row], rs);
    }
  }
  if (!isDiag) {
#pragma unroll
    for (int j = 0; j < 4; ++j) {
      float c = cs[j];
      c += __shfl_xor(c, 16);
      c += __shfl_xor(c, 32);
      if (quad == 0) atomicAdd(&denom[bn + wx * 64 + j * 16 + colq], c);
    }
  }
}

// ---------------- kernel 3: finalize loss scalar -------------------------
__global__ void __launch_bounds__(1024) finalize(
    const float* __restrict__ denom, const float* __restrict__ pos,
    float* __restrict__ out, int N) {
  __shared__ float red[16];
  const int tid = threadIdx.x;
  float s = 0.0f;
  for (int i = tid; i < N / 4; i += 1024) {
    float4 d = ((const float4*)denom)[i];
    float4 p = ((const float4*)pos)[i];
    s += __logf(d.x) - p.x * TEMP_INV;
    s += __logf(d.y) - p.y * TEMP_INV;
    s += __logf(d.z) - p.z * TEMP_INV;
    s += __logf(d.w) - p.w * TEMP_INV;
  }
  for (int off = 32; off; off >>= 1) s += __shfl_xor(s, off);
  if ((tid & 63) == 0) red[tid >> 6] = s;
  __syncthreads();
  if (tid < 16) {
    s = red[tid];
    s += __shfl_xor(s, 1);
    s += __shfl_xor(s, 2);
    s += __shfl_xor(s, 4);
    s += __shfl_xor(s, 8);
    if (tid == 0) out[0] = s / (float)N;
  }
}

extern "C" void kernel_launch(void* const* d_in, const int* in_sizes, int n_in,
                              void* d_out, int out_size, void* d_ws, size_t ws_size,
                              hipStream_t stream) {
  const float* zi = (const float*)d_in[0];
  const float* zj = (const float*)d_in[1];
  const int B = in_sizes[0] / D;  // 4096
  const int N = 2 * B;            // 8192

  __hip_bfloat16* zn = (__hip_bfloat16*)d_ws;
  float* denom = (float*)((char*)d_ws + (size_t)N * D * sizeof(__hip_bfloat16));
  float* pos = denom + N;

  normalize_rows<<<512, 256, 0, stream>>>(zi, zj, zn, denom, B);
  ntxent_gemm<<<NTILES, 256, 0, stream>>>(zn, denom, pos, B);
  finalize<<<1, 1024, 0, stream>>>(denom, pos, (float*)d_out, N);
}